// Round 5
// baseline (279.854 us; speedup 1.0000x reference)
//
#include <hip/hip_runtime.h>

// BondWeight: out[b, src+1, dst+1] = w; out[b, dst+1, src+1] = w (two passes,
// last-write-wins within the 1024-write per-batch sequence, numpy semantics).
// B=1024, E=512, T=8, N=256. Output 256 MB f32 -> pure HBM-write-bound (~42us).
//
// R5: stream loop reduced to pure ds_read_b128 -> global_store_dwordx4.
// R2-R4 streamed from a packed u16 seq|type table, costing 1 b64 + 4
// dependent divergent ds_read_b32 + ~16 VALU per float4 store; three
// rewrites around that loop were all neutral, so it is the prime suspect.
// Now: u16 CAS-max table (16 KB) resolves last-write-wins; a fixup phase
// writes the WINNER's f32 weight into a 32 KB f32 table (exactly one thread
// matches seqtab[cell]==pk per cell, so no race); stream copies LDS->global
// with zero VALU. 32-row chunk per block, 8 blocks/batch, 48 KB LDS.

#define NB_E 512
#define NB_N 256
#define CH_ROWS 32
#define SEQ_WORDS (CH_ROWS * NB_N / 2)   // 4096 u32 = 16 KB
#define W_FLOATS  (CH_ROWS * NB_N)       // 8192 f32 = 32 KB

typedef float v4f __attribute__((ext_vector_type(4)));

__device__ __forceinline__ void lds_max_u16(unsigned int* tab, int cell, unsigned int v16)
{
    unsigned int* w = tab + (cell >> 1);
    const int sh = (cell & 1) * 16;
    unsigned int old = *w;
    while (true) {
        const unsigned int cur = (old >> sh) & 0xFFFFu;
        if (cur >= v16) break;                       // current winner is later
        const unsigned int nw = (old & ~(0xFFFFu << sh)) | (v16 << sh);
        const unsigned int seen = atomicCAS(w, old, nw);
        if (seen == old) break;
        old = seen;                                  // contended: retry
    }
}

__global__ __launch_bounds__(256) void BondWeight_41738492182540_kernel(
    const float* __restrict__ weights,
    const int*   __restrict__ bsrc,
    const int*   __restrict__ bdst,
    const int*   __restrict__ btyp,
    float*       __restrict__ out)
{
    __shared__ unsigned int seqtab[SEQ_WORDS];
    __shared__ float        wtab[W_FLOATS];

    const int bx = blockIdx.x;
    const int b  = bx >> 3;                 // batch
    const int r0 = (bx & 7) * CH_ROWS;      // my 32-row window
    const int t  = threadIdx.x;

    // --- zero both tables (48 KB): 4 + 8 x b128 per thread ---
    {
        uint4* s4 = (uint4*)seqtab;
        #pragma unroll
        for (int k = 0; k < SEQ_WORDS / 4 / 256; ++k)
            s4[t + 256 * k] = make_uint4(0u, 0u, 0u, 0u);
        float4* w4 = (float4*)wtab;
        const float4 fz = make_float4(0.f, 0.f, 0.f, 0.f);
        #pragma unroll
        for (int k = 0; k < W_FLOATS / 4 / 256; ++k)
            w4[t + 256 * k] = fz;
    }

    // --- load my batch's edges: 2 per thread (int2, coalesced) ---
    // seq order: pass1 (src,dst) e=0..511 then pass2 (dst,src) e=0..511.
    // packed = (seq+1)<<3 | type  (max 8199 < 2^16); CAS-max == last wins.
    const int2 s2 = ((const int2*)(bsrc + b * NB_E))[t];
    const int2 d2 = ((const int2*)(bdst + b * NB_E))[t];
    const int2 y2 = ((const int2*)(btyp + b * NB_E))[t];
    const float wA = weights[y2.x & 7];      // tiny table, L1-broadcast
    const float wB = weights[y2.y & 7];

    int cell[4]; unsigned int pk[4]; float wv[4]; bool inw[4];
    {
        const int e0 = 2 * t, e1 = 2 * t + 1;
        const int sa = s2.x + 1, da = d2.x + 1;      // [1,255]
        const int sb = s2.y + 1, db = d2.y + 1;
        const unsigned int ta = (unsigned int)y2.x & 7u;
        const unsigned int tb = (unsigned int)y2.y & 7u;
        const int rr[4] = { sa, sb, da, db };
        const int cc[4] = { da, db, sa, sb };
        const unsigned int qq[4] = {
            ((unsigned int)(e0 + 1) << 3) | ta,
            ((unsigned int)(e1 + 1) << 3) | tb,
            ((unsigned int)(NB_E + e0 + 1) << 3) | ta,
            ((unsigned int)(NB_E + e1 + 1) << 3) | tb };
        const float ww[4] = { wA, wB, wA, wB };
        #pragma unroll
        for (int i = 0; i < 4; ++i) {
            const int r = rr[i] - r0;
            inw[i]  = (0 <= r) && (r < CH_ROWS);
            cell[i] = r * NB_N + cc[i];
            pk[i]   = qq[i];
            wv[i]   = ww[i];
        }
    }

    __syncthreads();    // tables zeroed

    // --- CAS-max scatter of writes landing in my window (~2/thread avg/8) ---
    #pragma unroll
    for (int i = 0; i < 4; ++i)
        if (inw[i]) lds_max_u16(seqtab, cell[i], pk[i]);

    __syncthreads();    // winners final

    // --- fixup: the unique winning thread writes the f32 weight ---
    #pragma unroll
    for (int i = 0; i < 4; ++i) {
        if (inw[i]) {
            const unsigned int w32 = seqtab[cell[i] >> 1];
            const unsigned int cur = (w32 >> ((cell[i] & 1) * 16)) & 0xFFFFu;
            if (cur == pk[i]) wtab[cell[i]] = wv[i];
        }
    }

    __syncthreads();    // wtab final

    // --- stream my 32 rows: 2048 float4, 8/thread, pure LDS->global copy ---
    v4f* __restrict__ out4 = ((v4f*)out)
        + (size_t)b * (NB_N * NB_N / 4) + r0 * (NB_N / 4);
    const v4f* __restrict__ w4 = (const v4f*)wtab;

    #pragma unroll
    for (int k = 0; k < W_FLOATS / 4 / 256; ++k) {
        const int i4 = t + 256 * k;
        out4[i4] = w4[i4];                   // ds_read_b128 + store_dwordx4
    }
}

extern "C" void kernel_launch(void* const* d_in, const int* in_sizes, int n_in,
                              void* d_out, int out_size, void* d_ws, size_t ws_size,
                              hipStream_t stream) {
    const float* weights = (const float*)d_in[0];   // [T=8]
    const int*   bsrc    = (const int*)d_in[1];     // [B, E]
    const int*   bdst    = (const int*)d_in[2];     // [B, E]
    const int*   btyp    = (const int*)d_in[3];     // [B, E]
    float*       out     = (float*)d_out;           // [B, N, N] f32

    const int nb = in_sizes[1] / NB_E;              // B = 1024

    BondWeight_41738492182540_kernel<<<nb * 8, 256, 0, stream>>>(
        weights, bsrc, bdst, btyp, out);
}